// Round 15
// baseline (302.433 us; speedup 1.0000x reference)
//
#include <hip/hip_runtime.h>
#include <hip/hip_bf16.h>

#define NN 50000
#define EE 640000
#define ABLK 625   // pass A/B blocks
#define AEDG 1024  // edges per pass A/B block (625*1024 = 640000 exactly)
#define NBK 196    // buckets of 256 nodes (dst>>8)

typedef __attribute__((ext_vector_type(8))) short short8;
typedef __attribute__((ext_vector_type(4))) float f32x4;

__device__ __forceinline__ float bf2f(ushort u) {
    return __uint_as_float(((uint)u) << 16);
}
__device__ __forceinline__ ushort f2bf(float f) {
    uint b = __float_as_uint(f);
    uint r = (b + 0x7fffu + ((b >> 16) & 1u)) >> 16;
    return (ushort)r;
}
__device__ __forceinline__ ushort f2bf_rn(float f) {
    return (ushort)((__float_as_uint(f) + 0x8000u) >> 16);
}

// ---- Pass A: LDS bucket histogram + eab packing; tail blocks: compose -----

__global__ __launch_bounds__(256) void k_bucketA(
    const int* __restrict__ ei, const float* __restrict__ ea,
    uint* __restrict__ eab, int* __restrict__ bcnt,
    const float* __restrict__ wn_all, const float* __restrict__ aw1,
    const float* __restrict__ wle, ushort* __restrict__ wcT) {
    const int t = threadIdx.x;
    if (blockIdx.x >= ABLK) {
        const int bb = blockIdx.x - ABLK;
        const int l = bb >> 7;
        const int k = bb & 127;
        const float* wn = wn_all + (l * 128 + k) * 128;
        float acc = 0.f;
        for (int c = 0; c < 128; ++c) {
            float cat;
            if (t < 128)
                cat = aw1[(l * 256 + ((t & 64) << 1) + c) * 64 + (t & 63)];
            else
                cat = wle[(l * 130 + c) * 128 + (t - 128)];
            acc += wn[c] * cat;
        }
        wcT[(l * 256 + t) * 128 + k] = f2bf(acc);
        return;
    }
    __shared__ int h[NBK];
    for (int i = t; i < NBK; i += 256) h[i] = 0;
    __syncthreads();
    const int base = blockIdx.x * AEDG;
    #pragma unroll
    for (int k = 0; k < 4; ++k) {
        const int e = base + k * 256 + t;
        const int d = ei[EE + e];
        atomicAdd(&h[d >> 8], 1);
        const float2 v = *(const float2*)(ea + 2 * e);
        eab[e] = ((uint)f2bf(v.y) << 16) | (uint)f2bf(v.x);
    }
    __syncthreads();
    for (int i = t; i < NBK; i += 256)
        bcnt[i * ABLK + blockIdx.x] = h[i];
}

// ---- Scan 1: per-bucket exclusive scan over 625 block counts --------------

__global__ __launch_bounds__(256) void k_scanbkt(const int* __restrict__ bcnt,
                                                 int* __restrict__ boff2,
                                                 int* __restrict__ tot) {
    const int b = blockIdx.x;
    const int t = threadIdx.x;
    const int lane = t & 63, wv = t >> 6;
    __shared__ int ws[4];
    int run = 0;
    for (int k = 0; k < 3; ++k) {
        const int j = k * 256 + t;
        const int v = (j < ABLK) ? bcnt[b * ABLK + j] : 0;
        int x = v;
        #pragma unroll
        for (int o = 1; o < 64; o <<= 1) {
            int y = __shfl_up(x, o);
            if (lane >= o) x += y;
        }
        if (lane == 63) ws[wv] = x;
        __syncthreads();
        int add = 0;
        for (int w = 0; w < wv; ++w) add += ws[w];
        if (j < ABLK) boff2[b * ABLK + j] = run + add + x - v;
        const int btot = ws[0] + ws[1] + ws[2] + ws[3];
        __syncthreads();
        run += btot;
    }
    if (t == 0) tot[b] = run;
}

// ---- Scan 2: exclusive scan of bucket totals -> bbase ---------------------

__global__ __launch_bounds__(256) void k_scantot(const int* __restrict__ tot,
                                                 int* __restrict__ bbase) {
    const int t = threadIdx.x;
    const int lane = t & 63, wv = t >> 6;
    const int v = (t < NBK) ? tot[t] : 0;
    int x = v;
    #pragma unroll
    for (int o = 1; o < 64; o <<= 1) {
        int y = __shfl_up(x, o);
        if (lane >= o) x += y;
    }
    __shared__ int ws[4];
    if (lane == 63) ws[wv] = x;
    __syncthreads();
    int add = 0;
    for (int w = 0; w < wv; ++w) add += ws[w];
    if (t < NBK) bbase[t] = add + x - v;
    if (t == 255) bbase[NBK] = add + x;  // == EE
}

// ---- Pass B: bucket-partitioned staging (block-private contiguous ranges) -

__global__ __launch_bounds__(256) void k_bucketB(const int* __restrict__ ei,
                                                 const uint* __restrict__ eab,
                                                 const int* __restrict__ bbase,
                                                 const int* __restrict__ boff2,
                                                 uint2* __restrict__ staged) {
    __shared__ int cur[NBK];
    const int t = threadIdx.x;
    for (int i = t; i < NBK; i += 256)
        cur[i] = bbase[i] + boff2[i * ABLK + blockIdx.x];
    __syncthreads();
    const int base = blockIdx.x * AEDG;
    #pragma unroll
    for (int k = 0; k < 4; ++k) {
        const int e = base + k * 256 + t;
        const int d = ei[EE + e];
        const uint s = (uint)ei[e];
        const int pos = atomicAdd(&cur[d >> 8], 1);
        staged[pos] = make_uint2(s | ((uint)(d & 255) << 20), eab[e]);
    }
}

// ---- Pass C: per-bucket finalize: offs + adjSE + csr_dst (L2-local) -------

__global__ __launch_bounds__(256) void k_bucketC(const int* __restrict__ bbase,
                                                 const uint2* __restrict__ staged,
                                                 uint2* __restrict__ adjSE,
                                                 int* __restrict__ offs,
                                                 int* __restrict__ csr_dst) {
    const int b = blockIdx.x;
    const int t = threadIdx.x;
    const int lane = t & 63, wv = t >> 6;
    const int sbeg = bbase[b], send = bbase[b + 1];

    __shared__ int cnt[256];
    __shared__ int cur[256];
    __shared__ int ws[4];
    cnt[t] = 0;
    __syncthreads();
    for (int i = sbeg + t; i < send; i += 256)
        atomicAdd(&cnt[(staged[i].x >> 20) & 255], 1);
    __syncthreads();

    const int v = cnt[t];
    int x = v;
    #pragma unroll
    for (int o = 1; o < 64; o <<= 1) {
        int y = __shfl_up(x, o);
        if (lane >= o) x += y;
    }
    if (lane == 63) ws[wv] = x;
    __syncthreads();
    int add = 0;
    for (int w = 0; w < wv; ++w) add += ws[w];
    const int excl = add + x - v;

    const int node = b * 256 + t;
    if (node <= NN) offs[node] = sbeg + excl;
    cur[t] = sbeg + excl;
    __syncthreads();

    for (int i = sbeg + t; i < send; i += 256) {
        const uint2 r = staged[i];
        const int din = (r.x >> 20) & 255;
        const int pos = atomicAdd(&cur[din], 1);
        adjSE[pos] = make_uint2(r.x & 0xFFFFFu, r.y);
        csr_dst[pos] = b * 256 + din;
    }
}

// ---- K1: pqr = x @ Wc   [N,128]x[128,256] -> bf16 [N,256] -----------------
// 32 rows/block (grid 1563 -> ~24 waves/CU, 2x latency hiding vs 64-row),
// B in registers (wcT is 64KB, L2-resident), A prefetched one tile ahead.

#define K1_LOADA(AV, RT)                                                   \
    {                                                                      \
        const float* xrow_ = xin + (size_t)(rbase + (RT) * 16 + lrow) * 128; \
        _Pragma("unroll")                                                  \
        for (int s = 0; s < 4; ++s) {                                      \
            const float* px = xrow_ + s * 32 + kg * 8;                     \
            float4 u = *(const float4*)(px);                               \
            float4 v = *(const float4*)(px + 4);                           \
            short8 av;                                                     \
            av[0] = (short)f2bf(u.x); av[1] = (short)f2bf(u.y);            \
            av[2] = (short)f2bf(u.z); av[3] = (short)f2bf(u.w);            \
            av[4] = (short)f2bf(v.x); av[5] = (short)f2bf(v.y);            \
            av[6] = (short)f2bf(v.z); av[7] = (short)f2bf(v.w);            \
            AV[s] = av;                                                    \
        }                                                                  \
    }

#define K1_COMP(AV, RT)                                                    \
    {                                                                      \
        f32x4 acc[4] = {};                                                 \
        _Pragma("unroll")                                                  \
        for (int t = 0; t < 4; ++t) {                                      \
            _Pragma("unroll")                                              \
            for (int s = 0; s < 4; ++s)                                    \
                acc[t] = __builtin_amdgcn_mfma_f32_16x16x32_bf16(          \
                    AV[s], b[t][s], acc[t], 0, 0, 0);                      \
        }                                                                  \
        _Pragma("unroll")                                                  \
        for (int t = 0; t < 4; ++t) {                                      \
            const int col = c0 + t * 16 + lrow;                            \
            _Pragma("unroll")                                              \
            for (int j = 0; j < 4; ++j)                                    \
                pqr[(size_t)(rbase + (RT) * 16 + kg * 4 + j) * 256 + col] = \
                    f2bf(acc[t][j]);                                       \
        }                                                                  \
    }

__global__ __launch_bounds__(256) void k1_gemm(const float* __restrict__ xin,
                                               const ushort* __restrict__ wcT,
                                               ushort* __restrict__ pqr) {
    const int wave = threadIdx.x >> 6;
    const int lane = threadIdx.x & 63;
    const int rbase = blockIdx.x * 32;
    const int c0 = wave * 64;
    const int lrow = lane & 15;
    const int kg = lane >> 4;

    short8 b[4][4];
    #pragma unroll
    for (int t = 0; t < 4; ++t) {
        const int col = c0 + t * 16 + lrow;
        #pragma unroll
        for (int s = 0; s < 4; ++s)
            b[t][s] = *(const short8*)(wcT + col * 128 + s * 32 + kg * 8);
    }

    if (rbase + 32 <= NN) {
        short8 aA[4], aB[4];
        K1_LOADA(aA, 0)
        K1_LOADA(aB, 1) K1_COMP(aA, 0)
        K1_COMP(aB, 1)
    } else {
        #pragma unroll
        for (int rt = 0; rt < 2; ++rt) {
            const int r0 = rbase + rt * 16;
            int arow = r0 + lrow;
            if (arow >= NN) arow = NN - 1;
            const float* xrow = xin + (size_t)arow * 128;
            short8 a[4];
            #pragma unroll
            for (int s = 0; s < 4; ++s) {
                const float* px = xrow + s * 32 + kg * 8;
                float4 u = *(const float4*)(px);
                float4 v = *(const float4*)(px + 4);
                short8 av;
                av[0] = (short)f2bf(u.x); av[1] = (short)f2bf(u.y);
                av[2] = (short)f2bf(u.z); av[3] = (short)f2bf(u.w);
                av[4] = (short)f2bf(v.x); av[5] = (short)f2bf(v.y);
                av[6] = (short)f2bf(v.z); av[7] = (short)f2bf(v.w);
                a[s] = av;
            }
            f32x4 acc[4] = {};
            #pragma unroll
            for (int t = 0; t < 4; ++t) {
                #pragma unroll
                for (int s = 0; s < 4; ++s)
                    acc[t] = __builtin_amdgcn_mfma_f32_16x16x32_bf16(a[s], b[t][s], acc[t], 0, 0, 0);
            }
            #pragma unroll
            for (int t = 0; t < 4; ++t) {
                const int col = c0 + t * 16 + lrow;
                #pragma unroll
                for (int j = 0; j < 4; ++j) {
                    const int orow = r0 + kg * 4 + j;
                    if (orow < NN)
                        pqr[(size_t)orow * 256 + col] = f2bf(acc[t][j]);
                }
            }
        }
    }
}

// ---- K_att: edge-parallel attention scores via MFMA -----------------------
// One wave = 64 edges = 4 MFMA tiles sharing one B fragment (col0 = w2).
// Reads adjSE/csr_dst sequentially, writes attv float4 coalesced.

__global__ __launch_bounds__(256) void k_att(
    const uint2* __restrict__ adjSE, const int* __restrict__ csr_dst,
    float* __restrict__ attv, const ushort* __restrict__ pqr,
    const float* __restrict__ b1v, const float* __restrict__ w2v,
    const float* __restrict__ b2v) {
    const int lane = threadIdx.x & 63;
    const int e0 = blockIdx.x * 256 + (threadIdx.x >> 6) * 64;
    const int row = lane & 15;
    const int kg = lane >> 4;
    const float b2 = b2v[0];

    short8 bv0, bv1;
    const bool col0 = (row == 0);
    #pragma unroll
    for (int j = 0; j < 8; ++j) {
        bv0[j] = (short)f2bf(col0 ? w2v[kg * 8 + j] : 0.f);
        bv1[j] = (short)f2bf(col0 ? w2v[32 + kg * 8 + j] : 0.f);
    }

    uint srcs[4], dsts[4];
    #pragma unroll
    for (int t = 0; t < 4; ++t) {
        const int pos = e0 + t * 16 + row;
        srcs[t] = adjSE[pos].x;
        dsts[t] = (uint)csr_dst[pos];
    }

    f32x4 acc[4] = {};
    #pragma unroll
    for (int h = 0; h < 2; ++h) {
        const int cb = 32 * h + kg * 8;
        float4 bA = *(const float4*)(b1v + cb);
        float4 bB = *(const float4*)(b1v + cb + 4);
        const short8 bfrag = h ? bv1 : bv0;
        #pragma unroll
        for (int t = 0; t < 4; ++t) {
            short8 qv = *(const short8*)(pqr + (size_t)srcs[t] * 256 + 64 + cb);
            short8 pv = *(const short8*)(pqr + (size_t)dsts[t] * 256 + cb);
            short8 av;
            #pragma unroll
            for (int j = 0; j < 8; ++j) {
                float bb = (j < 4) ? ((const float*)&bA)[j] : ((const float*)&bB)[j - 4];
                float v = bf2f((ushort)qv[j]) + bf2f((ushort)pv[j]) + bb;
                av[j] = (short)f2bf_rn(fmaxf(v, 0.f));
            }
            acc[t] = __builtin_amdgcn_mfma_f32_16x16x32_bf16(av, bfrag, acc[t], 0, 0, 0);
        }
    }
    if (row == 0) {
        #pragma unroll
        for (int t = 0; t < 4; ++t) {
            float4 o;
            #pragma unroll
            for (int j = 0; j < 4; ++j) {
                float s = acc[t][j] + b2;
                ((float*)&o)[j] = 1.f / (1.f + __expf(-s));
            }
            *(float4*)(attv + e0 + t * 16 + kg * 4) = o;
        }
    }
}

// ---- K_msg: 1 wave/node, A/B-quad pipeline, zero rotation -----------------
// Per edge: adjSE (8B seq) + attv (4B seq) + ONE 4B gather + 4 FMA.
// Epilogue loads hoisted before the loop (issue-early latency hiding).

#define CONS(MM, AA, RR, JJ)                                          \
    {                                                                 \
        const float a_ = ((JJ) < ee) ? (AA) : 0.f;                    \
        acc0 = fmaf(a_, __uint_as_float((RR) << 16), acc0);           \
        acc1 = fmaf(a_, __uint_as_float((RR) & 0xffff0000u), acc1);   \
        sE0  = fmaf(a_, __uint_as_float((MM).y << 16), sE0);          \
        sE1  = fmaf(a_, __uint_as_float((MM).y & 0xffff0000u), sE1);  \
    }

#define LOADQ(M0, M1, M2, M3, A0, A1, A2, A3, R0, R1, R2, R3, BASE)  \
    {                                                                \
        M0 = adjSE[(BASE)];                                          \
        M1 = adjSE[(BASE) + 1];                                      \
        M2 = adjSE[(BASE) + 2];                                      \
        M3 = adjSE[(BASE) + 3];                                      \
        A0 = attv[(BASE)];                                           \
        A1 = attv[(BASE) + 1];                                       \
        A2 = attv[(BASE) + 2];                                       \
        A3 = attv[(BASE) + 3];                                       \
        R0 = *(const uint*)(rp + (size_t)M0.x * 256);                \
        R1 = *(const uint*)(rp + (size_t)M1.x * 256);                \
        R2 = *(const uint*)(rp + (size_t)M2.x * 256);                \
        R3 = *(const uint*)(rp + (size_t)M3.x * 256);                \
    }

__global__ __launch_bounds__(256) void k_msg(
    const int* __restrict__ offs, const uint2* __restrict__ adjSE,
    const float* __restrict__ attv, const ushort* __restrict__ pqr,
    const float* __restrict__ xin, const float* __restrict__ web,
    const float* __restrict__ biasv, const float* __restrict__ gammav,
    const float* __restrict__ betav, float* __restrict__ xout, int do_relu) {
    const int lane = threadIdx.x & 63;
    const int n = blockIdx.x * 4 + (threadIdx.x >> 6);
    const int c0 = 2 * lane;

    const int eb = __builtin_amdgcn_readfirstlane(offs[n]);
    const int ee = __builtin_amdgcn_readfirstlane(offs[n + 1]);

    const float web00 = web[c0], web01 = web[c0 + 1];
    const float web10 = web[128 + c0], web11 = web[128 + c0 + 1];
    const float2 bi = *(const float2*)(biasv + c0);
    const float2 ga = *(const float2*)(gammav + c0);
    const float2 be = *(const float2*)(betav + c0);
    const float2 xr = *(const float2*)(xin + (size_t)n * 128 + c0);

    float acc0 = 0.f, acc1 = 0.f, sE0 = 0.f, sE1 = 0.f;
    if (eb < ee) {
        const ushort* rp = pqr + 128 + c0;
        uint2 a0, a1, a2, a3, b0, b1, b2, b3;
        float fa0, fa1, fa2, fa3, fb0, fb1, fb2, fb3;
        uint ra0, ra1, ra2, ra3, rb0, rb1, rb2, rb3;
        LOADQ(a0, a1, a2, a3, fa0, fa1, fa2, fa3, ra0, ra1, ra2, ra3, eb);
        LOADQ(b0, b1, b2, b3, fb0, fb1, fb2, fb3, rb0, rb1, rb2, rb3, eb + 4);
        int j = eb;
        for (; j + 8 < ee; j += 8) {
            CONS(a0, fa0, ra0, j) CONS(a1, fa1, ra1, j + 1)
            CONS(a2, fa2, ra2, j + 2) CONS(a3, fa3, ra3, j + 3)
            LOADQ(a0, a1, a2, a3, fa0, fa1, fa2, fa3, ra0, ra1, ra2, ra3, j + 8);
            CONS(b0, fb0, rb0, j + 4) CONS(b1, fb1, rb1, j + 5)
            CONS(b2, fb2, rb2, j + 6) CONS(b3, fb3, rb3, j + 7)
            LOADQ(b0, b1, b2, b3, fb0, fb1, fb2, fb3, rb0, rb1, rb2, rb3, j + 12);
        }
        CONS(a0, fa0, ra0, j) CONS(a1, fa1, ra1, j + 1)
        CONS(a2, fa2, ra2, j + 2) CONS(a3, fa3, ra3, j + 3)
        CONS(b0, fb0, rb0, j + 4) CONS(b1, fb1, rb1, j + 5)
        CONS(b2, fb2, rb2, j + 6) CONS(b3, fb3, rb3, j + 7)
    }

    acc0 += sE0 * web00 + sE1 * web10;
    acc1 += sE0 * web01 + sE1 * web11;

    float v0 = acc0 + bi.x;
    float v1 = acc1 + bi.y;
    float sm = v0 + v1, sq = v0 * v0 + v1 * v1;
    #pragma unroll
    for (int o = 32; o > 0; o >>= 1) {
        sm += __shfl_xor(sm, o);
        sq += __shfl_xor(sq, o);
    }
    const float mean = sm * (1.f / 128.f);
    const float var = sq * (1.f / 128.f) - mean * mean;
    const float inv = rsqrtf(var + 1e-5f);
    float y0 = (v0 - mean) * inv * ga.x + be.x;
    float y1 = (v1 - mean) * inv * ga.y + be.y;
    if (do_relu) { y0 = fmaxf(y0, 0.f); y1 = fmaxf(y1, 0.f); }
    y0 += xr.x;
    y1 += xr.y;
    float2 o2; o2.x = y0; o2.y = y1;
    *(float2*)(xout + (size_t)n * 128 + c0) = o2;
}

// ---------------------------------------------------------------------------

extern "C" void kernel_launch(void* const* d_in, const int* in_sizes, int n_in,
                              void* d_out, int out_size, void* d_ws, size_t ws_size,
                              hipStream_t stream) {
    const float* x   = (const float*)d_in[0];
    const int*   ei  = (const int*)d_in[1];
    const float* ea  = (const float*)d_in[2];
    const float* wn  = (const float*)d_in[3];
    const float* wle = (const float*)d_in[4];
    const float* aw1 = (const float*)d_in[5];
    const float* ab1 = (const float*)d_in[6];
    const float* aw2 = (const float*)d_in[7];
    const float* ab2 = (const float*)d_in[8];
    const float* bia = (const float*)d_in[9];
    const float* gam = (const float*)d_in[10];
    const float* bet = (const float*)d_in[11];

    char* w = (char*)d_ws;
    size_t o = 0;
    auto alloc = [&](size_t bytes) {
        char* p = w + o;
        o = (o + bytes + 255) & ~(size_t)255;
        return p;
    };
    int*    offs    = (int*)alloc((size_t)(NN + 1) * 4);
    int*    bcnt    = (int*)alloc((size_t)NBK * ABLK * 4);
    int*    boff2   = (int*)alloc((size_t)NBK * ABLK * 4);
    int*    tot     = (int*)alloc((size_t)NBK * 4);
    int*    bbase   = (int*)alloc((size_t)(NBK + 1) * 4);
    uint*   eab     = (uint*)alloc((size_t)EE * 4);
    uint2*  staged  = (uint2*)alloc((size_t)EE * 8);
    int*    csr_dst = (int*)alloc((size_t)EE * 4);
    uint2*  adjSE   = (uint2*)alloc((size_t)(EE + 64) * 8);
    float*  attv    = (float*)alloc((size_t)(EE + 64) * 4);
    ushort* wcT     = (ushort*)alloc((size_t)3 * 256 * 128 * 2);
    ushort* pqr     = (ushort*)alloc((size_t)NN * 256 * 2);
    float*  xb1     = (float*)alloc((size_t)NN * 128 * 4);
    float*  xb2     = (float*)alloc((size_t)NN * 128 * 4);

    hipMemsetAsync(adjSE + EE, 0, (size_t)64 * 8, stream);
    hipMemsetAsync(attv + EE, 0, (size_t)64 * 4, stream);
    k_bucketA<<<ABLK + 384, 256, 0, stream>>>(ei, ea, eab, bcnt, wn, aw1, wle, wcT);
    k_scanbkt<<<NBK, 256, 0, stream>>>(bcnt, boff2, tot);
    k_scantot<<<1, 256, 0, stream>>>(tot, bbase);
    k_bucketB<<<ABLK, 256, 0, stream>>>(ei, eab, bbase, boff2, staged);
    k_bucketC<<<NBK, 256, 0, stream>>>(bbase, staged, adjSE, offs, csr_dst);

    const float* xi = x;
    float* xo = xb1;
    for (int l = 0; l < 3; ++l) {
        k1_gemm<<<(NN + 31) / 32, 256, 0, stream>>>(xi, wcT + (size_t)l * 256 * 128, pqr);
        k_att<<<EE / 256, 256, 0, stream>>>(adjSE, csr_dst, attv, pqr,
                                            ab1 + l * 64, aw2 + l * 64, ab2 + l);
        const bool last = (l == 2);
        float* out_ptr = last ? (float*)d_out : xo;
        k_msg<<<NN / 4, 256, 0, stream>>>(
            offs, adjSE, attv, pqr, xi,
            wle + ((size_t)l * 130 + 128) * 128,
            bia + l * 128, gam + l * 128, bet + l * 128,
            out_ptr, last ? 0 : 1);
        xi = out_ptr;
        xo = (l == 0) ? xb2 : xb1;
    }
}

// Round 16
// 287.015 us; speedup vs baseline: 1.0537x; 1.0537x over previous
//
#include <hip/hip_runtime.h>
#include <hip/hip_bf16.h>

#define NN 50000
#define EE 640000
#define ABLK 625   // pass A/B blocks
#define AEDG 1024  // edges per pass A/B block (625*1024 = 640000 exactly)
#define NBK 196    // buckets of 256 nodes (dst>>8)

typedef __attribute__((ext_vector_type(8))) short short8;
typedef __attribute__((ext_vector_type(4))) float f32x4;

__device__ __forceinline__ float bf2f(ushort u) {
    return __uint_as_float(((uint)u) << 16);
}
__device__ __forceinline__ ushort f2bf(float f) {
    uint b = __float_as_uint(f);
    uint r = (b + 0x7fffu + ((b >> 16) & 1u)) >> 16;
    return (ushort)r;
}
__device__ __forceinline__ ushort f2bf_rn(float f) {
    return (ushort)((__float_as_uint(f) + 0x8000u) >> 16);
}

// ---- Pass A: LDS bucket histogram + eab packing; tail blocks: compose -----

__global__ __launch_bounds__(256) void k_bucketA(
    const int* __restrict__ ei, const float* __restrict__ ea,
    uint* __restrict__ eab, int* __restrict__ bcnt,
    const float* __restrict__ wn_all, const float* __restrict__ aw1,
    const float* __restrict__ wle, ushort* __restrict__ wcT) {
    const int t = threadIdx.x;
    if (blockIdx.x >= ABLK) {
        const int bb = blockIdx.x - ABLK;
        const int l = bb >> 7;
        const int k = bb & 127;
        const float* wn = wn_all + (l * 128 + k) * 128;
        float acc = 0.f;
        for (int c = 0; c < 128; ++c) {
            float cat;
            if (t < 128)
                cat = aw1[(l * 256 + ((t & 64) << 1) + c) * 64 + (t & 63)];
            else
                cat = wle[(l * 130 + c) * 128 + (t - 128)];
            acc += wn[c] * cat;
        }
        wcT[(l * 256 + t) * 128 + k] = f2bf(acc);
        return;
    }
    __shared__ int h[NBK];
    for (int i = t; i < NBK; i += 256) h[i] = 0;
    __syncthreads();
    const int base = blockIdx.x * AEDG;
    #pragma unroll
    for (int k = 0; k < 4; ++k) {
        const int e = base + k * 256 + t;
        const int d = ei[EE + e];
        atomicAdd(&h[d >> 8], 1);
        const float2 v = *(const float2*)(ea + 2 * e);
        eab[e] = ((uint)f2bf(v.y) << 16) | (uint)f2bf(v.x);
    }
    __syncthreads();
    for (int i = t; i < NBK; i += 256)
        bcnt[i * ABLK + blockIdx.x] = h[i];
}

// ---- Scan 1: per-bucket exclusive scan over 625 block counts --------------

__global__ __launch_bounds__(256) void k_scanbkt(const int* __restrict__ bcnt,
                                                 int* __restrict__ boff2,
                                                 int* __restrict__ tot) {
    const int b = blockIdx.x;
    const int t = threadIdx.x;
    const int lane = t & 63, wv = t >> 6;
    __shared__ int ws[4];
    int run = 0;
    for (int k = 0; k < 3; ++k) {
        const int j = k * 256 + t;
        const int v = (j < ABLK) ? bcnt[b * ABLK + j] : 0;
        int x = v;
        #pragma unroll
        for (int o = 1; o < 64; o <<= 1) {
            int y = __shfl_up(x, o);
            if (lane >= o) x += y;
        }
        if (lane == 63) ws[wv] = x;
        __syncthreads();
        int add = 0;
        for (int w = 0; w < wv; ++w) add += ws[w];
        if (j < ABLK) boff2[b * ABLK + j] = run + add + x - v;
        const int btot = ws[0] + ws[1] + ws[2] + ws[3];
        __syncthreads();
        run += btot;
    }
    if (t == 0) tot[b] = run;
}

// ---- Scan 2: exclusive scan of bucket totals -> bbase; zero tail pads -----

__global__ __launch_bounds__(256) void k_scantot(const int* __restrict__ tot,
                                                 int* __restrict__ bbase,
                                                 uint2* __restrict__ adjSE,
                                                 float* __restrict__ attv) {
    const int t = threadIdx.x;
    const int lane = t & 63, wv = t >> 6;
    const int v = (t < NBK) ? tot[t] : 0;
    int x = v;
    #pragma unroll
    for (int o = 1; o < 64; o <<= 1) {
        int y = __shfl_up(x, o);
        if (lane >= o) x += y;
    }
    __shared__ int ws[4];
    if (lane == 63) ws[wv] = x;
    __syncthreads();
    int add = 0;
    for (int w = 0; w < wv; ++w) add += ws[w];
    if (t < NBK) bbase[t] = add + x - v;
    if (t == 255) bbase[NBK] = add + x;  // == EE
    if (t < 64) {                        // zero pads read by k_msg prefetch
        adjSE[EE + t] = make_uint2(0u, 0u);
        attv[EE + t] = 0.f;
    }
}

// ---- Pass B: bucket-partitioned staging (block-private contiguous ranges) -

__global__ __launch_bounds__(256) void k_bucketB(const int* __restrict__ ei,
                                                 const uint* __restrict__ eab,
                                                 const int* __restrict__ bbase,
                                                 const int* __restrict__ boff2,
                                                 uint2* __restrict__ staged) {
    __shared__ int cur[NBK];
    const int t = threadIdx.x;
    for (int i = t; i < NBK; i += 256)
        cur[i] = bbase[i] + boff2[i * ABLK + blockIdx.x];
    __syncthreads();
    const int base = blockIdx.x * AEDG;
    #pragma unroll
    for (int k = 0; k < 4; ++k) {
        const int e = base + k * 256 + t;
        const int d = ei[EE + e];
        const uint s = (uint)ei[e];
        const int pos = atomicAdd(&cur[d >> 8], 1);
        staged[pos] = make_uint2(s | ((uint)(d & 255) << 20), eab[e]);
    }
}

// ---- Pass C: per-bucket finalize: offs + adjSE + csr_dst (L2-local) -------

__global__ __launch_bounds__(256) void k_bucketC(const int* __restrict__ bbase,
                                                 const uint2* __restrict__ staged,
                                                 uint2* __restrict__ adjSE,
                                                 int* __restrict__ offs,
                                                 int* __restrict__ csr_dst) {
    const int b = blockIdx.x;
    const int t = threadIdx.x;
    const int lane = t & 63, wv = t >> 6;
    const int sbeg = bbase[b], send = bbase[b + 1];

    __shared__ int cnt[256];
    __shared__ int cur[256];
    __shared__ int ws[4];
    cnt[t] = 0;
    __syncthreads();
    for (int i = sbeg + t; i < send; i += 256)
        atomicAdd(&cnt[(staged[i].x >> 20) & 255], 1);
    __syncthreads();

    const int v = cnt[t];
    int x = v;
    #pragma unroll
    for (int o = 1; o < 64; o <<= 1) {
        int y = __shfl_up(x, o);
        if (lane >= o) x += y;
    }
    if (lane == 63) ws[wv] = x;
    __syncthreads();
    int add = 0;
    for (int w = 0; w < wv; ++w) add += ws[w];
    const int excl = add + x - v;

    const int node = b * 256 + t;
    if (node <= NN) offs[node] = sbeg + excl;
    cur[t] = sbeg + excl;
    __syncthreads();

    for (int i = sbeg + t; i < send; i += 256) {
        const uint2 r = staged[i];
        const int din = (r.x >> 20) & 255;
        const int pos = atomicAdd(&cur[din], 1);
        adjSE[pos] = make_uint2(r.x & 0xFFFFFu, r.y);
        csr_dst[pos] = b * 256 + din;
    }
}

// ---- K1: pqr = x @ Wc   [N,128]x[128,256] -> bf16 [N,256] -----------------
// 64 rows/block (best measured; 16/32-row both slower), B in registers,
// A prefetched one row-tile ahead.

#define K1_LOADA(AV, RT)                                                   \
    {                                                                      \
        const float* xrow_ = xin + (size_t)(rbase + (RT) * 16 + lrow) * 128; \
        _Pragma("unroll")                                                  \
        for (int s = 0; s < 4; ++s) {                                      \
            const float* px = xrow_ + s * 32 + kg * 8;                     \
            float4 u = *(const float4*)(px);                               \
            float4 v = *(const float4*)(px + 4);                           \
            short8 av;                                                     \
            av[0] = (short)f2bf(u.x); av[1] = (short)f2bf(u.y);            \
            av[2] = (short)f2bf(u.z); av[3] = (short)f2bf(u.w);            \
            av[4] = (short)f2bf(v.x); av[5] = (short)f2bf(v.y);            \
            av[6] = (short)f2bf(v.z); av[7] = (short)f2bf(v.w);            \
            AV[s] = av;                                                    \
        }                                                                  \
    }

#define K1_COMP(AV, RT)                                                    \
    {                                                                      \
        f32x4 acc[4] = {};                                                 \
        _Pragma("unroll")                                                  \
        for (int t = 0; t < 4; ++t) {                                      \
            _Pragma("unroll")                                              \
            for (int s = 0; s < 4; ++s)                                    \
                acc[t] = __builtin_amdgcn_mfma_f32_16x16x32_bf16(          \
                    AV[s], b[t][s], acc[t], 0, 0, 0);                      \
        }                                                                  \
        _Pragma("unroll")                                                  \
        for (int t = 0; t < 4; ++t) {                                      \
            const int col = c0 + t * 16 + lrow;                            \
            _Pragma("unroll")                                              \
            for (int j = 0; j < 4; ++j)                                    \
                pqr[(size_t)(rbase + (RT) * 16 + kg * 4 + j) * 256 + col] = \
                    f2bf(acc[t][j]);                                       \
        }                                                                  \
    }

__global__ __launch_bounds__(256) void k1_gemm(const float* __restrict__ xin,
                                               const ushort* __restrict__ wcT,
                                               ushort* __restrict__ pqr) {
    const int wave = threadIdx.x >> 6;
    const int lane = threadIdx.x & 63;
    const int rbase = blockIdx.x * 64;
    const int c0 = wave * 64;
    const int lrow = lane & 15;
    const int kg = lane >> 4;

    short8 b[4][4];
    #pragma unroll
    for (int t = 0; t < 4; ++t) {
        const int col = c0 + t * 16 + lrow;
        #pragma unroll
        for (int s = 0; s < 4; ++s)
            b[t][s] = *(const short8*)(wcT + col * 128 + s * 32 + kg * 8);
    }

    if (rbase + 64 <= NN) {
        short8 aA[4], aB[4];
        K1_LOADA(aA, 0)
        K1_LOADA(aB, 1) K1_COMP(aA, 0)
        K1_LOADA(aA, 2) K1_COMP(aB, 1)
        K1_LOADA(aB, 3) K1_COMP(aA, 2)
        K1_COMP(aB, 3)
    } else {
        #pragma unroll
        for (int rt = 0; rt < 4; ++rt) {
            const int r0 = rbase + rt * 16;
            int arow = r0 + lrow;
            if (arow >= NN) arow = NN - 1;
            const float* xrow = xin + (size_t)arow * 128;
            short8 a[4];
            #pragma unroll
            for (int s = 0; s < 4; ++s) {
                const float* px = xrow + s * 32 + kg * 8;
                float4 u = *(const float4*)(px);
                float4 v = *(const float4*)(px + 4);
                short8 av;
                av[0] = (short)f2bf(u.x); av[1] = (short)f2bf(u.y);
                av[2] = (short)f2bf(u.z); av[3] = (short)f2bf(u.w);
                av[4] = (short)f2bf(v.x); av[5] = (short)f2bf(v.y);
                av[6] = (short)f2bf(v.z); av[7] = (short)f2bf(v.w);
                a[s] = av;
            }
            f32x4 acc[4] = {};
            #pragma unroll
            for (int t = 0; t < 4; ++t) {
                #pragma unroll
                for (int s = 0; s < 4; ++s)
                    acc[t] = __builtin_amdgcn_mfma_f32_16x16x32_bf16(a[s], b[t][s], acc[t], 0, 0, 0);
            }
            #pragma unroll
            for (int t = 0; t < 4; ++t) {
                const int col = c0 + t * 16 + lrow;
                #pragma unroll
                for (int j = 0; j < 4; ++j) {
                    const int orow = r0 + kg * 4 + j;
                    if (orow < NN)
                        pqr[(size_t)orow * 256 + col] = f2bf(acc[t][j]);
                }
            }
        }
    }
}

// ---- K_att: edge-parallel attention scores via MFMA -----------------------
// One wave = 64 edges = 4 MFMA tiles sharing one B fragment (col0 = w2).
// Reads adjSE/csr_dst sequentially, writes attv float4 coalesced.

__global__ __launch_bounds__(256) void k_att(
    const uint2* __restrict__ adjSE, const int* __restrict__ csr_dst,
    float* __restrict__ attv, const ushort* __restrict__ pqr,
    const float* __restrict__ b1v, const float* __restrict__ w2v,
    const float* __restrict__ b2v) {
    const int lane = threadIdx.x & 63;
    const int e0 = blockIdx.x * 256 + (threadIdx.x >> 6) * 64;
    const int row = lane & 15;
    const int kg = lane >> 4;
    const float b2 = b2v[0];

    short8 bv0, bv1;
    const bool col0 = (row == 0);
    #pragma unroll
    for (int j = 0; j < 8; ++j) {
        bv0[j] = (short)f2bf(col0 ? w2v[kg * 8 + j] : 0.f);
        bv1[j] = (short)f2bf(col0 ? w2v[32 + kg * 8 + j] : 0.f);
    }

    uint srcs[4], dsts[4];
    #pragma unroll
    for (int t = 0; t < 4; ++t) {
        const int pos = e0 + t * 16 + row;
        srcs[t] = adjSE[pos].x;
        dsts[t] = (uint)csr_dst[pos];
    }

    f32x4 acc[4] = {};
    #pragma unroll
    for (int h = 0; h < 2; ++h) {
        const int cb = 32 * h + kg * 8;
        float4 bA = *(const float4*)(b1v + cb);
        float4 bB = *(const float4*)(b1v + cb + 4);
        const short8 bfrag = h ? bv1 : bv0;
        #pragma unroll
        for (int t = 0; t < 4; ++t) {
            short8 qv = *(const short8*)(pqr + (size_t)srcs[t] * 256 + 64 + cb);
            short8 pv = *(const short8*)(pqr + (size_t)dsts[t] * 256 + cb);
            short8 av;
            #pragma unroll
            for (int j = 0; j < 8; ++j) {
                float bb = (j < 4) ? ((const float*)&bA)[j] : ((const float*)&bB)[j - 4];
                float v = bf2f((ushort)qv[j]) + bf2f((ushort)pv[j]) + bb;
                av[j] = (short)f2bf_rn(fmaxf(v, 0.f));
            }
            acc[t] = __builtin_amdgcn_mfma_f32_16x16x32_bf16(av, bfrag, acc[t], 0, 0, 0);
        }
    }
    if (row == 0) {
        #pragma unroll
        for (int t = 0; t < 4; ++t) {
            float4 o;
            #pragma unroll
            for (int j = 0; j < 4; ++j) {
                float s = acc[t][j] + b2;
                ((float*)&o)[j] = 1.f / (1.f + __expf(-s));
            }
            *(float4*)(attv + e0 + t * 16 + kg * 4) = o;
        }
    }
}

// ---- K_msg: 1 wave/node, A/B-quad pipeline, zero rotation -----------------
// Per edge: adjSE (8B seq) + attv (4B seq) + ONE 4B gather + 4 FMA.
// Epilogue loads hoisted before the loop (issue-early latency hiding).

#define CONS(MM, AA, RR, JJ)                                          \
    {                                                                 \
        const float a_ = ((JJ) < ee) ? (AA) : 0.f;                    \
        acc0 = fmaf(a_, __uint_as_float((RR) << 16), acc0);           \
        acc1 = fmaf(a_, __uint_as_float((RR) & 0xffff0000u), acc1);   \
        sE0  = fmaf(a_, __uint_as_float((MM).y << 16), sE0);          \
        sE1  = fmaf(a_, __uint_as_float((MM).y & 0xffff0000u), sE1);  \
    }

#define LOADQ(M0, M1, M2, M3, A0, A1, A2, A3, R0, R1, R2, R3, BASE)  \
    {                                                                \
        M0 = adjSE[(BASE)];                                          \
        M1 = adjSE[(BASE) + 1];                                      \
        M2 = adjSE[(BASE) + 2];                                      \
        M3 = adjSE[(BASE) + 3];                                      \
        A0 = attv[(BASE)];                                           \
        A1 = attv[(BASE) + 1];                                       \
        A2 = attv[(BASE) + 2];                                       \
        A3 = attv[(BASE) + 3];                                       \
        R0 = *(const uint*)(rp + (size_t)M0.x * 256);                \
        R1 = *(const uint*)(rp + (size_t)M1.x * 256);                \
        R2 = *(const uint*)(rp + (size_t)M2.x * 256);                \
        R3 = *(const uint*)(rp + (size_t)M3.x * 256);                \
    }

__global__ __launch_bounds__(256) void k_msg(
    const int* __restrict__ offs, const uint2* __restrict__ adjSE,
    const float* __restrict__ attv, const ushort* __restrict__ pqr,
    const float* __restrict__ xin, const float* __restrict__ web,
    const float* __restrict__ biasv, const float* __restrict__ gammav,
    const float* __restrict__ betav, float* __restrict__ xout, int do_relu) {
    const int lane = threadIdx.x & 63;
    const int n = blockIdx.x * 4 + (threadIdx.x >> 6);
    const int c0 = 2 * lane;

    const int eb = __builtin_amdgcn_readfirstlane(offs[n]);
    const int ee = __builtin_amdgcn_readfirstlane(offs[n + 1]);

    const float web00 = web[c0], web01 = web[c0 + 1];
    const float web10 = web[128 + c0], web11 = web[128 + c0 + 1];
    const float2 bi = *(const float2*)(biasv + c0);
    const float2 ga = *(const float2*)(gammav + c0);
    const float2 be = *(const float2*)(betav + c0);
    const float2 xr = *(const float2*)(xin + (size_t)n * 128 + c0);

    float acc0 = 0.f, acc1 = 0.f, sE0 = 0.f, sE1 = 0.f;
    if (eb < ee) {
        const ushort* rp = pqr + 128 + c0;
        uint2 a0, a1, a2, a3, b0, b1, b2, b3;
        float fa0, fa1, fa2, fa3, fb0, fb1, fb2, fb3;
        uint ra0, ra1, ra2, ra3, rb0, rb1, rb2, rb3;
        LOADQ(a0, a1, a2, a3, fa0, fa1, fa2, fa3, ra0, ra1, ra2, ra3, eb);
        LOADQ(b0, b1, b2, b3, fb0, fb1, fb2, fb3, rb0, rb1, rb2, rb3, eb + 4);
        int j = eb;
        for (; j + 8 < ee; j += 8) {
            CONS(a0, fa0, ra0, j) CONS(a1, fa1, ra1, j + 1)
            CONS(a2, fa2, ra2, j + 2) CONS(a3, fa3, ra3, j + 3)
            LOADQ(a0, a1, a2, a3, fa0, fa1, fa2, fa3, ra0, ra1, ra2, ra3, j + 8);
            CONS(b0, fb0, rb0, j + 4) CONS(b1, fb1, rb1, j + 5)
            CONS(b2, fb2, rb2, j + 6) CONS(b3, fb3, rb3, j + 7)
            LOADQ(b0, b1, b2, b3, fb0, fb1, fb2, fb3, rb0, rb1, rb2, rb3, j + 12);
        }
        CONS(a0, fa0, ra0, j) CONS(a1, fa1, ra1, j + 1)
        CONS(a2, fa2, ra2, j + 2) CONS(a3, fa3, ra3, j + 3)
        CONS(b0, fb0, rb0, j + 4) CONS(b1, fb1, rb1, j + 5)
        CONS(b2, fb2, rb2, j + 6) CONS(b3, fb3, rb3, j + 7)
    }

    acc0 += sE0 * web00 + sE1 * web10;
    acc1 += sE0 * web01 + sE1 * web11;

    float v0 = acc0 + bi.x;
    float v1 = acc1 + bi.y;
    float sm = v0 + v1, sq = v0 * v0 + v1 * v1;
    #pragma unroll
    for (int o = 32; o > 0; o >>= 1) {
        sm += __shfl_xor(sm, o);
        sq += __shfl_xor(sq, o);
    }
    const float mean = sm * (1.f / 128.f);
    const float var = sq * (1.f / 128.f) - mean * mean;
    const float inv = rsqrtf(var + 1e-5f);
    float y0 = (v0 - mean) * inv * ga.x + be.x;
    float y1 = (v1 - mean) * inv * ga.y + be.y;
    if (do_relu) { y0 = fmaxf(y0, 0.f); y1 = fmaxf(y1, 0.f); }
    y0 += xr.x;
    y1 += xr.y;
    float2 o2; o2.x = y0; o2.y = y1;
    *(float2*)(xout + (size_t)n * 128 + c0) = o2;
}

// ---------------------------------------------------------------------------

extern "C" void kernel_launch(void* const* d_in, const int* in_sizes, int n_in,
                              void* d_out, int out_size, void* d_ws, size_t ws_size,
                              hipStream_t stream) {
    const float* x   = (const float*)d_in[0];
    const int*   ei  = (const int*)d_in[1];
    const float* ea  = (const float*)d_in[2];
    const float* wn  = (const float*)d_in[3];
    const float* wle = (const float*)d_in[4];
    const float* aw1 = (const float*)d_in[5];
    const float* ab1 = (const float*)d_in[6];
    const float* aw2 = (const float*)d_in[7];
    const float* ab2 = (const float*)d_in[8];
    const float* bia = (const float*)d_in[9];
    const float* gam = (const float*)d_in[10];
    const float* bet = (const float*)d_in[11];

    char* w = (char*)d_ws;
    size_t o = 0;
    auto alloc = [&](size_t bytes) {
        char* p = w + o;
        o = (o + bytes + 255) & ~(size_t)255;
        return p;
    };
    int*    offs    = (int*)alloc((size_t)(NN + 1) * 4);
    int*    bcnt    = (int*)alloc((size_t)NBK * ABLK * 4);
    int*    boff2   = (int*)alloc((size_t)NBK * ABLK * 4);
    int*    tot     = (int*)alloc((size_t)NBK * 4);
    int*    bbase   = (int*)alloc((size_t)(NBK + 1) * 4);
    uint*   eab     = (uint*)alloc((size_t)EE * 4);
    uint2*  staged  = (uint2*)alloc((size_t)EE * 8);
    int*    csr_dst = (int*)alloc((size_t)EE * 4);
    uint2*  adjSE   = (uint2*)alloc((size_t)(EE + 64) * 8);
    float*  attv    = (float*)alloc((size_t)(EE + 64) * 4);
    ushort* wcT     = (ushort*)alloc((size_t)3 * 256 * 128 * 2);
    ushort* pqr     = (ushort*)alloc((size_t)NN * 256 * 2);
    float*  xb1     = (float*)alloc((size_t)NN * 128 * 4);
    float*  xb2     = (float*)alloc((size_t)NN * 128 * 4);

    k_bucketA<<<ABLK + 384, 256, 0, stream>>>(ei, ea, eab, bcnt, wn, aw1, wle, wcT);
    k_scanbkt<<<NBK, 256, 0, stream>>>(bcnt, boff2, tot);
    k_scantot<<<1, 256, 0, stream>>>(tot, bbase, adjSE, attv);
    k_bucketB<<<ABLK, 256, 0, stream>>>(ei, eab, bbase, boff2, staged);
    k_bucketC<<<NBK, 256, 0, stream>>>(bbase, staged, adjSE, offs, csr_dst);

    const float* xi = x;
    float* xo = xb1;
    for (int l = 0; l < 3; ++l) {
        k1_gemm<<<(NN + 63) / 64, 256, 0, stream>>>(xi, wcT + (size_t)l * 256 * 128, pqr);
        k_att<<<EE / 256, 256, 0, stream>>>(adjSE, csr_dst, attv, pqr,
                                            ab1 + l * 64, aw2 + l * 64, ab2 + l);
        const bool last = (l == 2);
        float* out_ptr = last ? (float*)d_out : xo;
        k_msg<<<NN / 4, 256, 0, stream>>>(
            offs, adjSE, attv, pqr, xi,
            wle + ((size_t)l * 130 + 128) * 128,
            bia + l * 128, gam + l * 128, bet + l * 128,
            out_ptr, last ? 0 : 1);
        xi = out_ptr;
        xo = (l == 0) ? xb2 : xb1;
    }
}